// Round 1
// baseline (73.152 us; speedup 1.0000x reference)
//
#include <hip/hip_runtime.h>

#define N_REGIONS 17
#define N_CH 7
#define ROWS_ 82
#define COLS_ 67
#define N_MAP (ROWS_ * COLS_)            // 5494 cells in the grid
#define ELEMS_PER_B (N_MAP * N_CH)       // 38458 floats per batch
// total output elements = BATCH * ELEMS_PER_B = 78,761,984 (divisible by 4)

__global__ void init_map_k(int* __restrict__ map) {
    int i = blockIdx.x * blockDim.x + threadIdx.x;
    if (i < N_MAP) map[i] = -1;
}

__global__ void scatter_map_k(const int* __restrict__ cell_lin,
                              const int* __restrict__ region_ids,
                              int n, int* __restrict__ map) {
    int i = blockIdx.x * blockDim.x + threadIdx.x;
    if (i < n) {
        int c = cell_lin[i];                 // cell index = rows*COLS + cols = cell_lin itself
        if (c >= 0 && c < N_MAP) map[c] = region_ids[i];
    }
}

__global__ __launch_bounds__(256) void fill_k(const float* __restrict__ x,
                                              const int* __restrict__ map,
                                              float* __restrict__ out,
                                              unsigned total4) {
    unsigned stride = gridDim.x * blockDim.x;
    for (unsigned t = blockIdx.x * blockDim.x + threadIdx.x; t < total4; t += stride) {
        unsigned e0 = t * 4u;
        float4 v;
        float* vp = reinterpret_cast<float*>(&v);
#pragma unroll
        for (int j = 0; j < 4; ++j) {
            unsigned e = e0 + (unsigned)j;
            unsigned b = e / ELEMS_PER_B;            // magic-mul
            unsigned rem = e - b * ELEMS_PER_B;
            unsigned cell = rem / N_CH;              // magic-mul
            unsigned ch = rem - cell * N_CH;
            int reg = map[cell];                     // L1-resident, 22 KB
            vp[j] = (reg >= 0) ? x[b * (N_REGIONS * N_CH) + reg * N_CH + ch] : 0.0f;
        }
        *reinterpret_cast<float4*>(out + e0) = v;    // coalesced 16B/lane store
    }
}

extern "C" void kernel_launch(void* const* d_in, const int* in_sizes, int n_in,
                              void* d_out, int out_size, void* d_ws, size_t ws_size,
                              hipStream_t stream) {
    const float* x        = (const float*)d_in[0];
    const int* cell_lin   = (const int*)d_in[1];
    const int* region_ids = (const int*)d_in[2];
    float* out = (float*)d_out;
    int* map = (int*)d_ws;
    int n_cells = in_sizes[1];

    init_map_k<<<(N_MAP + 255) / 256, 256, 0, stream>>>(map);
    scatter_map_k<<<(n_cells + 255) / 256, 256, 0, stream>>>(cell_lin, region_ids, n_cells, map);

    unsigned total4 = (unsigned)out_size / 4u;
    fill_k<<<2048, 256, 0, stream>>>(x, map, out, total4);
}

// Round 3
// 72.964 us; speedup vs baseline: 1.0026x; 1.0026x over previous
//
#include <hip/hip_runtime.h>

#define N_REGIONS 17
#define N_CH 7
#define ROWS_ 82
#define COLS_ 67
#define N_MAP (ROWS_ * COLS_)        // 5494 cells in the grid
#define EPB (N_MAP * N_CH)           // 38458 floats per batch (== 2 mod 4)
#define PAIR (2 * EPB)               // 76916 floats per 2 batches (== 0 mod 4)
#define XROW (N_REGIONS * N_CH)      // 119 floats per batch of x

typedef float f32x4 __attribute__((ext_vector_type(4)));

// total output = 2048 * 38458 = 1024 * 76916 = 78,761,984 floats (exact)

__global__ void init_table_k(short* __restrict__ t) {
    int i = blockIdx.x * blockDim.x + threadIdx.x;
    if (i < PAIR) t[i] = -1;
}

__global__ void scatter_table_k(const int* __restrict__ cell_lin,
                                const int* __restrict__ region_ids,
                                int n, short* __restrict__ t) {
    int i = blockIdx.x * blockDim.x + threadIdx.x;
    if (i >= n) return;
    int c = cell_lin[i];
    int r = region_ids[i];
    if (c < 0 || c >= N_MAP) return;
#pragma unroll
    for (int lb = 0; lb < 2; ++lb) {
        int dst = lb * EPB + c * N_CH;
        short src = (short)(lb * XROW + r * N_CH);
#pragma unroll
        for (int ch = 0; ch < N_CH; ++ch) t[dst + ch] = (short)(src + ch);
    }
}

__global__ __launch_bounds__(256) void fill2_k(const float* __restrict__ x,
                                               const short* __restrict__ t,
                                               float* __restrict__ out,
                                               unsigned total4) {
    unsigned stride = gridDim.x * blockDim.x;
    for (unsigned i = blockIdx.x * blockDim.x + threadIdx.x; i < total4; i += stride) {
        unsigned e0 = i * 4u;
        unsigned p = e0 / PAIR;              // magic-mul (one divide per 4 elements)
        unsigned off = e0 - p * PAIR;        // multiple of 4 -> 8B-aligned table read
        short4 s = *reinterpret_cast<const short4*>(t + off);
        const float* xb = x + p * (2 * XROW);
        f32x4 v;
        v.x = (s.x >= 0) ? xb[s.x] : 0.0f;
        v.y = (s.y >= 0) ? xb[s.y] : 0.0f;
        v.z = (s.z >= 0) ? xb[s.z] : 0.0f;
        v.w = (s.w >= 0) ? xb[s.w] : 0.0f;
        __builtin_nontemporal_store(v, reinterpret_cast<f32x4*>(out + e0));
    }
}

extern "C" void kernel_launch(void* const* d_in, const int* in_sizes, int n_in,
                              void* d_out, int out_size, void* d_ws, size_t ws_size,
                              hipStream_t stream) {
    const float* x        = (const float*)d_in[0];
    const int* cell_lin   = (const int*)d_in[1];
    const int* region_ids = (const int*)d_in[2];
    float* out = (float*)d_out;
    short* table = (short*)d_ws;          // 76916 * 2 B = 150 KB of scratch
    int n_cells = in_sizes[1];

    init_table_k<<<(PAIR + 255) / 256, 256, 0, stream>>>(table);
    scatter_table_k<<<(n_cells + 255) / 256, 256, 0, stream>>>(cell_lin, region_ids, n_cells, table);

    unsigned total4 = (unsigned)out_size / 4u;
    fill2_k<<<2048, 256, 0, stream>>>(x, table, out, total4);
}